// Round 11
// baseline (123.611 us; speedup 1.0000x reference)
//
#include <hip/hip_runtime.h>
#include <math.h>

#define GN 50000
#define GE 800000
#define INF 128
#define OUTF 64
#define LRELU_ALPHA 0.2f

#define BUCK_SH 4                          // bucket = dst >> 4  (16 dsts/bucket)
#define BUCKW   16
#define NB      ((GN + BUCKW - 1) / BUCKW) // 3125 buckets (= 50000/16 exactly)
#define GT      ((GN + 63) / 64)           // 782 GEMM tiles (64 nodes each)
#define CHUNK   4096                       // edges per mscatter block
#define NCH     ((GE + CHUNK - 1) / CHUNK) // 196 chunks
#define CAP     384                        // bucket capacity (mean 256, +8 sigma)

// ---- bf16 helpers (RNE pack, cheap unpack) --------------------------------
__device__ __forceinline__ unsigned short f32_to_bf16(float f) {
    unsigned int u = __float_as_uint(f);
    return (unsigned short)((u + 0x7fffu + ((u >> 16) & 1u)) >> 16);
}
__device__ __forceinline__ float bf16lo(unsigned int u) { return __uint_as_float(u << 16); }
__device__ __forceinline__ float bf16hi(unsigned int u) { return __uint_as_float(u & 0xffff0000u); }

// ---------------------------------------------------------------------------
// K1 "front": blocks [0,NCH) run the edge multisplit (dispatched FIRST so the
// latency-bound scatter overlaps the VALU-bound GEMM); blocks [NCH, NCH+GT)
// run the GEMM (Wh=h@W -> bf16, s1/s2 fp32).
// Multisplit: CHUNK=4096, fully-unrolled register stash (pk/bb arrays) so all
// 16 edge loads are issued up-front -> 16x MLP per thread. This structure
// measured ~9 us; the CHUNK=16384 two-pass variant regressed to ~72 us
// (serial load->atomic chain at 1 wave/SIMD) — do not repeat.
// hist+run = 2*3125 ints = 25 KB, fits the 32 KB Wlds union.
// ---------------------------------------------------------------------------
__global__ __launch_bounds__(256) void k_front(const float* __restrict__ h,
                                               const float* __restrict__ W,
                                               const float* __restrict__ a,
                                               const int* __restrict__ src,
                                               const int* __restrict__ dst,
                                               unsigned short* __restrict__ Whb,
                                               float* __restrict__ s1,
                                               float* __restrict__ s2,
                                               int* __restrict__ ccount,
                                               int* __restrict__ epacked) {
    __shared__ __align__(16) float Wlds[INF * OUTF];  // 32 KB (unioned below)
    int t = threadIdx.x;

    if (blockIdx.x < NCH) {
        // ================= multisplit half =================
        int* hist = (int*)Wlds;          // NB ints
        int* run  = hist + NB;           // NB ints (25 KB total, fits union)
        for (int i = t; i < NB; i += 256) hist[i] = 0;
        __syncthreads();

        int base = blockIdx.x * CHUNK;
        int pk[CHUNK / 256];
        int bb[CHUNK / 256];
        #pragma unroll
        for (int i = 0; i < CHUNK / 256; ++i) {
            int e = base + i * 256 + t;
            if (e < GE) {
                int d = dst[e];
                int b = d >> BUCK_SH;
                pk[i] = (src[e] << BUCK_SH) | (d & (BUCKW - 1));
                bb[i] = b;
                atomicAdd(&hist[b], 1);
            } else {
                bb[i] = -1;
            }
        }
        __syncthreads();
        for (int i = t; i < NB; i += 256) {
            int c = hist[i];
            if (c > 0) run[i] = i * CAP + atomicAdd(&ccount[i], c);
        }
        __syncthreads();
        #pragma unroll
        for (int i = 0; i < CHUNK / 256; ++i) {
            if (bb[i] >= 0) {
                int pos = atomicAdd(&run[bb[i]], 1);
                epacked[pos] = pk[i];
            }
        }
    } else {
        // ================= GEMM half =================
        for (int i = t * 4; i < INF * OUTF; i += 256 * 4)
            *(float4*)&Wlds[i] = *(const float4*)&W[i];
        __syncthreads();

        int fg = t & 15;           // feature group: 4 feats
        int ng = t >> 4;           // node group: 4 nodes
        int jg = fg * 4;
        int n0 = (blockIdx.x - NCH) * 64 + ng * 4;

        int m0 = n0 + 0 < GN ? n0 + 0 : GN - 1;   // clamp loads; stores guarded
        int m1 = n0 + 1 < GN ? n0 + 1 : GN - 1;
        int m2 = n0 + 2 < GN ? n0 + 2 : GN - 1;
        int m3 = n0 + 3 < GN ? n0 + 3 : GN - 1;
        const float* h0 = &h[m0 * INF];
        const float* h1 = &h[m1 * INF];
        const float* h2 = &h[m2 * INF];
        const float* h3 = &h[m3 * INF];

        float4 acc0 = {0.f,0.f,0.f,0.f}, acc1 = acc0, acc2 = acc0, acc3 = acc0;
        for (int kc = 0; kc < INF; kc += 4) {
            float4 hv0 = *(const float4*)&h0[kc];
            float4 hv1 = *(const float4*)&h1[kc];
            float4 hv2 = *(const float4*)&h2[kc];
            float4 hv3 = *(const float4*)&h3[kc];
            #pragma unroll
            for (int kk = 0; kk < 4; ++kk) {
                float4 wv = *(float4*)&Wlds[(kc + kk) * OUTF + jg];
                float a0 = ((const float*)&hv0)[kk];
                float a1v = ((const float*)&hv1)[kk];
                float a2v = ((const float*)&hv2)[kk];
                float a3 = ((const float*)&hv3)[kk];
                acc0.x += a0 * wv.x; acc0.y += a0 * wv.y; acc0.z += a0 * wv.z; acc0.w += a0 * wv.w;
                acc1.x += a1v * wv.x; acc1.y += a1v * wv.y; acc1.z += a1v * wv.z; acc1.w += a1v * wv.w;
                acc2.x += a2v * wv.x; acc2.y += a2v * wv.y; acc2.z += a2v * wv.z; acc2.w += a2v * wv.w;
                acc3.x += a3 * wv.x; acc3.y += a3 * wv.y; acc3.z += a3 * wv.z; acc3.w += a3 * wv.w;
            }
        }

        float4 accs[4] = {acc0, acc1, acc2, acc3};
        #pragma unroll
        for (int i = 0; i < 4; ++i) {
            if (n0 + i < GN) {
                ushort4 p;
                p.x = f32_to_bf16(accs[i].x); p.y = f32_to_bf16(accs[i].y);
                p.z = f32_to_bf16(accs[i].z); p.w = f32_to_bf16(accs[i].w);
                *(ushort4*)&Whb[(n0 + i) * OUTF + jg] = p;
            }
        }

        float4 va1 = *(const float4*)&a[jg];
        float4 va2 = *(const float4*)&a[OUTF + jg];
        float p1[4], p2[4];
        #pragma unroll
        for (int i = 0; i < 4; ++i) {
            p1[i] = accs[i].x * va1.x + accs[i].y * va1.y + accs[i].z * va1.z + accs[i].w * va1.w;
            p2[i] = accs[i].x * va2.x + accs[i].y * va2.y + accs[i].z * va2.z + accs[i].w * va2.w;
        }
        #pragma unroll
        for (int off = 8; off >= 1; off >>= 1) {
            #pragma unroll
            for (int i = 0; i < 4; ++i) {
                p1[i] += __shfl_down(p1[i], off, 16);
                p2[i] += __shfl_down(p2[i], off, 16);
            }
        }
        if (fg == 0) {
            #pragma unroll
            for (int i = 0; i < 4; ++i) {
                if (n0 + i < GN) { s1[n0 + i] = p1[i]; s2[n0 + i] = p2[i]; }
            }
        }
    }
}

// ---------------------------------------------------------------------------
// K2: fused sort + softmax + aggregation + ELU, one block per 16-dst bucket,
// 128 threads. BUCKW halved again (the axis that won R3->R5): 3125 blocks
// (12.2/CU, ~24 waves/CU TLP), per-block serial depth halves. Pass A: int2
// read, 2 edges/thread covers the mean-256 bucket in ONE latency round +
// guarded scalar tail [256,384). Scan over 16 bins. Aggregation: proven
// single-buffer round, 16 groups x 8 lanes, one dst each.
// Failed K2 variants (do not repeat): 16-deep per-lane dual-buffer (+9.5us,
// VGPR pressure); 2-team 512-thr split (+4us, coordination); striped row
// (+27us, read amplification); LDS float-atomic accumulate (+290us, CAS-
// class ds atomics, bank-conflict counter saturated).
// ---------------------------------------------------------------------------
__global__ __launch_bounds__(128) void k_fgather(const int* __restrict__ ccount,
                                                 const int* __restrict__ epacked,
                                                 const float* __restrict__ s1,
                                                 const float* __restrict__ s2,
                                                 const unsigned short* __restrict__ Whb,
                                                 float* __restrict__ out) {
    __shared__ int2 sorted2[CAP];         // (pk, ex) sorted by dst slot (3 KB)
    __shared__ int hist[BUCKW];
    __shared__ int cur[BUCKW];
    __shared__ int cstart[BUCKW + 1];
    __shared__ float s2l[BUCKW];

    int t = threadIdx.x;
    int b = blockIdx.x;
    int dstbase = b * BUCKW;              // NB*BUCKW == GN exactly -> nd = BUCKW
    if (t < BUCKW) {
        hist[t] = 0;
        s2l[t] = s2[dstbase + t];
    }
    __syncthreads();

    int cnt = ccount[b]; if (cnt > CAP) cnt = CAP;   // safety only
    const int* row = &epacked[b * CAP];

    // ---- pass A: int2 row read (2 edges/thread, slots [0,256)) + guarded
    //      scalar tail (slots [256,CAP)) + dst hist + softmax score ----
    int i0 = t * 2;
    int pka[3]; float exa[3];
    pka[0] = pka[1] = pka[2] = -1;
    if (i0 < cnt) {
        int2 r2 = *(const int2*)&row[i0];     // CAP even -> 8B aligned
        #pragma unroll
        for (int k = 0; k < 2; ++k) {
            if (i0 + k < cnt) {
                int pk = (k == 0) ? r2.x : r2.y;
                pka[k] = pk;
                atomicAdd(&hist[pk & (BUCKW - 1)], 1);
                float x = s1[pk >> BUCK_SH] + s2l[pk & (BUCKW - 1)];
                x = (x > 0.f) ? x : LRELU_ALPHA * x;
                exa[k] = __expf(x);
            }
        }
    }
    {
        int it = 256 + t;                     // tail: at most 1 slot/thread
        if (it < cnt) {
            int pk = row[it];
            pka[2] = pk;
            atomicAdd(&hist[pk & (BUCKW - 1)], 1);
            float x = s1[pk >> BUCK_SH] + s2l[pk & (BUCKW - 1)];
            x = (x > 0.f) ? x : LRELU_ALPHA * x;
            exa[2] = __expf(x);
        }
    }
    __syncthreads();

    // ---- inclusive scan of 16 dst bins ----
    if (t < BUCKW) {
        int v = hist[t];
        int incl = v;
        #pragma unroll
        for (int off = 1; off < BUCKW; off <<= 1) {
            int u = __shfl_up(incl, off, BUCKW);
            if (t >= off) incl += u;
        }
        cstart[t + 1] = incl;
        cur[t] = incl - v;
        if (t == 0) cstart[0] = 0;
    }
    __syncthreads();

    // ---- pass B: counting-sort scatter from registers ----
    #pragma unroll
    for (int k = 0; k < 3; ++k) {
        if (pka[k] >= 0) {
            int pos = atomicAdd(&cur[pka[k] & (BUCKW - 1)], 1);
            sorted2[pos] = make_int2(pka[k], __float_as_int(exa[k]));
        }
    }
    __syncthreads();

    // ---- aggregation: 16 groups x 8 lanes (8 feats/lane), one dst/group ----
    int grp  = t >> 3;                    // 0..15: dst slot
    int lane = t & 7;
    int jg   = lane * 8;
    int dl   = grp;
    int c0 = cstart[dl], c1 = cstart[dl + 1];
    float acc[8] = {0.f,0.f,0.f,0.f,0.f,0.f,0.f,0.f};
    float den = 0.f;
    for (int cb = c0; cb < c1; cb += 8) {
        int m = c1 - cb; if (m > 8) m = 8;
        int   sj[8]; float exj[8];
        #pragma unroll
        for (int j = 0; j < 8; ++j) {
            if (j < m) {
                int2 pe = sorted2[cb + j];   // broadcast within 8-lane group
                sj[j]  = pe.x >> BUCK_SH;
                exj[j] = __uint_as_float(pe.y);
            }
        }
        uint4 wv[8];
        #pragma unroll
        for (int j = 0; j < 8; ++j)
            if (j < m) wv[j] = *(const uint4*)&Whb[sj[j] * OUTF + jg];
        #pragma unroll
        for (int j = 0; j < 8; ++j) {
            if (j < m) {
                float ex = exj[j];
                den += ex;
                acc[0] += ex * bf16lo(wv[j].x); acc[1] += ex * bf16hi(wv[j].x);
                acc[2] += ex * bf16lo(wv[j].y); acc[3] += ex * bf16hi(wv[j].y);
                acc[4] += ex * bf16lo(wv[j].z); acc[5] += ex * bf16hi(wv[j].z);
                acc[6] += ex * bf16lo(wv[j].w); acc[7] += ex * bf16hi(wv[j].w);
            }
        }
    }
    {
        float inv = (c1 > c0) ? 1.f / den : 0.f;
        float o[8];
        #pragma unroll
        for (int j = 0; j < 8; ++j) {
            float v = acc[j] * inv;
            o[j] = (v > 0.f) ? v : expm1f(v);
        }
        float* op = &out[(dstbase + dl) * OUTF + jg];
        *(float4*)(op + 0) = make_float4(o[0], o[1], o[2], o[3]);
        *(float4*)(op + 4) = make_float4(o[4], o[5], o[6], o[7]);
    }
}

extern "C" void kernel_launch(void* const* d_in, const int* in_sizes, int n_in,
                              void* d_out, int out_size, void* d_ws, size_t ws_size,
                              hipStream_t stream) {
    const float* h  = (const float*)d_in[0];
    const int*   ei = (const int*)d_in[1];    // [2, E]: first E = src, next E = dst
    const float* W  = (const float*)d_in[2];
    const float* a  = (const float*)d_in[3];
    const int* src = ei;
    const int* dst = ei + GE;

    float* ws = (float*)d_ws;
    float* s1 = ws;                                          // N
    float* s2 = s1 + GN;                                     // N
    unsigned short* Whb = (unsigned short*)(s2 + GN);        // N*64 bf16
    int* epacked = (int*)(Whb + (size_t)GN * OUTF);          // NB*CAP (4.8 MB)
    int* ccount  = epacked + (size_t)NB * CAP;               // NB
    float* out = (float*)d_out;

    hipMemsetAsync(ccount, 0, NB * sizeof(int), stream);     // 12.5 KB, capture-safe
    k_front<<<NCH + GT, 256, 0, stream>>>(h, W, a, src, dst, Whb, s1, s2,
                                          ccount, epacked);
    k_fgather<<<NB, 128, 0, stream>>>(ccount, epacked, s1, s2, Whb, out);
}

// Round 12
// 118.713 us; speedup vs baseline: 1.0413x; 1.0413x over previous
//
#include <hip/hip_runtime.h>
#include <math.h>

#define GN 50000
#define GE 800000
#define INF 128
#define OUTF 64
#define LRELU_ALPHA 0.2f

#define BUCK_SH 5                          // bucket = dst >> 5  (32 dsts/bucket)
#define BUCKW   32
#define NB      ((GN + BUCKW - 1) / BUCKW) // 1563 buckets
#define GT      ((GN + 63) / 64)           // 782 GEMM tiles (64 nodes each)
#define CHUNK   4096                       // edges per mscatter block
#define NCH     ((GE + CHUNK - 1) / CHUNK) // 196 chunks
#define CAP     768                        // bucket capacity (mean 512, +11 sigma)

// ---- bf16 helpers (RNE pack, cheap unpack) --------------------------------
__device__ __forceinline__ unsigned short f32_to_bf16(float f) {
    unsigned int u = __float_as_uint(f);
    return (unsigned short)((u + 0x7fffu + ((u >> 16) & 1u)) >> 16);
}
__device__ __forceinline__ float bf16lo(unsigned int u) { return __uint_as_float(u << 16); }
__device__ __forceinline__ float bf16hi(unsigned int u) { return __uint_as_float(u & 0xffff0000u); }

// ---------------------------------------------------------------------------
// K1 "front": blocks [0,NCH) run the edge multisplit (dispatched FIRST so the
// latency-bound scatter overlaps the VALU-bound GEMM); blocks [NCH, NCH+GT)
// run the GEMM (Wh=h@W -> bf16, s1/s2 fp32).
// Multisplit: CHUNK=4096, fully-unrolled register stash (pk/bb arrays) so all
// 16 edge loads are issued up-front -> 16x MLP per thread. This structure
// measured ~9 us; the CHUNK=16384 two-pass variant regressed to ~72 us
// (serial load->atomic chain at 1 wave/SIMD) — do not repeat.
// ---------------------------------------------------------------------------
__global__ __launch_bounds__(256) void k_front(const float* __restrict__ h,
                                               const float* __restrict__ W,
                                               const float* __restrict__ a,
                                               const int* __restrict__ src,
                                               const int* __restrict__ dst,
                                               unsigned short* __restrict__ Whb,
                                               float* __restrict__ s1,
                                               float* __restrict__ s2,
                                               int* __restrict__ ccount,
                                               int* __restrict__ epacked) {
    __shared__ __align__(16) float Wlds[INF * OUTF];  // 32 KB (unioned below)
    int t = threadIdx.x;

    if (blockIdx.x < NCH) {
        // ================= multisplit half =================
        int* hist = (int*)Wlds;          // NB ints
        int* run  = hist + NB;           // NB ints (12.5 KB total, fits union)
        for (int i = t; i < NB; i += 256) hist[i] = 0;
        __syncthreads();

        int base = blockIdx.x * CHUNK;
        int pk[CHUNK / 256];
        int bb[CHUNK / 256];
        #pragma unroll
        for (int i = 0; i < CHUNK / 256; ++i) {
            int e = base + i * 256 + t;
            if (e < GE) {
                int d = dst[e];
                int b = d >> BUCK_SH;
                pk[i] = (src[e] << BUCK_SH) | (d & (BUCKW - 1));
                bb[i] = b;
                atomicAdd(&hist[b], 1);
            } else {
                bb[i] = -1;
            }
        }
        __syncthreads();
        for (int i = t; i < NB; i += 256) {
            int c = hist[i];
            if (c > 0) run[i] = i * CAP + atomicAdd(&ccount[i], c);
        }
        __syncthreads();
        #pragma unroll
        for (int i = 0; i < CHUNK / 256; ++i) {
            if (bb[i] >= 0) {
                int pos = atomicAdd(&run[bb[i]], 1);
                epacked[pos] = pk[i];
            }
        }
    } else {
        // ================= GEMM half =================
        for (int i = t * 4; i < INF * OUTF; i += 256 * 4)
            *(float4*)&Wlds[i] = *(const float4*)&W[i];
        __syncthreads();

        int fg = t & 15;           // feature group: 4 feats
        int ng = t >> 4;           // node group: 4 nodes
        int jg = fg * 4;
        int n0 = (blockIdx.x - NCH) * 64 + ng * 4;

        int m0 = n0 + 0 < GN ? n0 + 0 : GN - 1;   // clamp loads; stores guarded
        int m1 = n0 + 1 < GN ? n0 + 1 : GN - 1;
        int m2 = n0 + 2 < GN ? n0 + 2 : GN - 1;
        int m3 = n0 + 3 < GN ? n0 + 3 : GN - 1;
        const float* h0 = &h[m0 * INF];
        const float* h1 = &h[m1 * INF];
        const float* h2 = &h[m2 * INF];
        const float* h3 = &h[m3 * INF];

        float4 acc0 = {0.f,0.f,0.f,0.f}, acc1 = acc0, acc2 = acc0, acc3 = acc0;
        for (int kc = 0; kc < INF; kc += 4) {
            float4 hv0 = *(const float4*)&h0[kc];
            float4 hv1 = *(const float4*)&h1[kc];
            float4 hv2 = *(const float4*)&h2[kc];
            float4 hv3 = *(const float4*)&h3[kc];
            #pragma unroll
            for (int kk = 0; kk < 4; ++kk) {
                float4 wv = *(float4*)&Wlds[(kc + kk) * OUTF + jg];
                float a0 = ((const float*)&hv0)[kk];
                float a1v = ((const float*)&hv1)[kk];
                float a2v = ((const float*)&hv2)[kk];
                float a3 = ((const float*)&hv3)[kk];
                acc0.x += a0 * wv.x; acc0.y += a0 * wv.y; acc0.z += a0 * wv.z; acc0.w += a0 * wv.w;
                acc1.x += a1v * wv.x; acc1.y += a1v * wv.y; acc1.z += a1v * wv.z; acc1.w += a1v * wv.w;
                acc2.x += a2v * wv.x; acc2.y += a2v * wv.y; acc2.z += a2v * wv.z; acc2.w += a2v * wv.w;
                acc3.x += a3 * wv.x; acc3.y += a3 * wv.y; acc3.z += a3 * wv.z; acc3.w += a3 * wv.w;
            }
        }

        float4 accs[4] = {acc0, acc1, acc2, acc3};
        #pragma unroll
        for (int i = 0; i < 4; ++i) {
            if (n0 + i < GN) {
                ushort4 p;
                p.x = f32_to_bf16(accs[i].x); p.y = f32_to_bf16(accs[i].y);
                p.z = f32_to_bf16(accs[i].z); p.w = f32_to_bf16(accs[i].w);
                *(ushort4*)&Whb[(n0 + i) * OUTF + jg] = p;
            }
        }

        float4 va1 = *(const float4*)&a[jg];
        float4 va2 = *(const float4*)&a[OUTF + jg];
        float p1[4], p2[4];
        #pragma unroll
        for (int i = 0; i < 4; ++i) {
            p1[i] = accs[i].x * va1.x + accs[i].y * va1.y + accs[i].z * va1.z + accs[i].w * va1.w;
            p2[i] = accs[i].x * va2.x + accs[i].y * va2.y + accs[i].z * va2.z + accs[i].w * va2.w;
        }
        #pragma unroll
        for (int off = 8; off >= 1; off >>= 1) {
            #pragma unroll
            for (int i = 0; i < 4; ++i) {
                p1[i] += __shfl_down(p1[i], off, 16);
                p2[i] += __shfl_down(p2[i], off, 16);
            }
        }
        if (fg == 0) {
            #pragma unroll
            for (int i = 0; i < 4; ++i) {
                if (n0 + i < GN) { s1[n0 + i] = p1[i]; s2[n0 + i] = p2[i]; }
            }
        }
    }
}

// ---------------------------------------------------------------------------
// K2: fused sort + softmax + aggregation + ELU, one block per 32-dst bucket,
// 256 threads (the proven structure; best measured total 119.0 us). Pass A
// reads the bucket row as int2 (2 edges/thread covers the mean-512 bucket in
// ONE serial latency round) with a guarded scalar tail for [512, CAP).
// Axis optima (measured, do not revisit): BUCKW 64 ✗ / 32 ✓ / 16 ✗;
// dense epacked ✓ / striped ✗ (+27us); CHUNK 4096 ✓ / 16384 ✗ (+72us);
// simple aggregation ✓ / dual-buffer ✗ (+9.5us) / 2-team ✗ (+4us) /
// LDS float-atomic ✗ (+290us, CAS-class ds atomics).
// ---------------------------------------------------------------------------
__global__ __launch_bounds__(256) void k_fgather(const int* __restrict__ ccount,
                                                 const int* __restrict__ epacked,
                                                 const float* __restrict__ s1,
                                                 const float* __restrict__ s2,
                                                 const unsigned short* __restrict__ Whb,
                                                 float* __restrict__ out) {
    __shared__ int2 sorted2[CAP];         // (pk, ex) sorted by dst slot
    __shared__ int hist[BUCKW];
    __shared__ int cur[BUCKW];
    __shared__ int cstart[BUCKW + 1];
    __shared__ float s2l[BUCKW];

    int t = threadIdx.x;
    int b = blockIdx.x;
    int dstbase = b * BUCKW;
    int nd = GN - dstbase; if (nd > BUCKW) nd = BUCKW;

    if (t < BUCKW) {
        hist[t] = 0;
        s2l[t] = (t < nd) ? s2[dstbase + t] : 0.f;
    }
    __syncthreads();

    int cnt = ccount[b]; if (cnt > CAP) cnt = CAP;   // safety only
    const int* row = &epacked[b * CAP];

    // ---- pass A: int2 row read (2 edges/thread, slots [0,512)) + guarded
    //      scalar tail (slots [512,CAP)) + dst hist + softmax score ----
    int i0 = t * 2;
    int pka[3]; float exa[3];
    pka[0] = pka[1] = pka[2] = -1;
    if (i0 < cnt) {
        int2 r2 = *(const int2*)&row[i0];     // CAP even -> 8B aligned
        #pragma unroll
        for (int k = 0; k < 2; ++k) {
            if (i0 + k < cnt) {
                int pk = (k == 0) ? r2.x : r2.y;
                pka[k] = pk;
                atomicAdd(&hist[pk & (BUCKW - 1)], 1);
                float x = s1[pk >> BUCK_SH] + s2l[pk & (BUCKW - 1)];
                x = (x > 0.f) ? x : LRELU_ALPHA * x;
                exa[k] = __expf(x);
            }
        }
    }
    {
        int it = 512 + t;                     // tail: at most 1 slot/thread
        if (it < cnt) {
            int pk = row[it];
            pka[2] = pk;
            atomicAdd(&hist[pk & (BUCKW - 1)], 1);
            float x = s1[pk >> BUCK_SH] + s2l[pk & (BUCKW - 1)];
            x = (x > 0.f) ? x : LRELU_ALPHA * x;
            exa[2] = __expf(x);
        }
    }
    __syncthreads();

    // ---- inclusive scan of 32 dst bins ----
    if (t < BUCKW) {
        int v = hist[t];
        int incl = v;
        #pragma unroll
        for (int off = 1; off < BUCKW; off <<= 1) {
            int u = __shfl_up(incl, off, BUCKW);
            if (t >= off) incl += u;
        }
        cstart[t + 1] = incl;
        cur[t] = incl - v;
        if (t == 0) cstart[0] = 0;
    }
    __syncthreads();

    // ---- pass B: counting-sort scatter from registers ----
    #pragma unroll
    for (int k = 0; k < 3; ++k) {
        if (pka[k] >= 0) {
            int pos = atomicAdd(&cur[pka[k] & (BUCKW - 1)], 1);
            sorted2[pos] = make_int2(pka[k], __float_as_int(exa[k]));
        }
    }
    __syncthreads();

    // ---- aggregation: 32 groups x 8 lanes (8 feats/lane), one dst/group ----
    int grp  = t >> 3;
    int lane = t & 7;
    int jg   = lane * 8;
    int dl   = grp;
    int c0 = cstart[dl], c1 = cstart[dl + 1];
    float acc[8] = {0.f,0.f,0.f,0.f,0.f,0.f,0.f,0.f};
    float den = 0.f;
    for (int cb = c0; cb < c1; cb += 8) {
        int m = c1 - cb; if (m > 8) m = 8;
        int   sj[8]; float exj[8];
        #pragma unroll
        for (int j = 0; j < 8; ++j) {
            if (j < m) {
                int2 pe = sorted2[cb + j];   // broadcast within 8-lane group
                sj[j]  = pe.x >> BUCK_SH;
                exj[j] = __uint_as_float(pe.y);
            }
        }
        uint4 wv[8];
        #pragma unroll
        for (int j = 0; j < 8; ++j)
            if (j < m) wv[j] = *(const uint4*)&Whb[sj[j] * OUTF + jg];
        #pragma unroll
        for (int j = 0; j < 8; ++j) {
            if (j < m) {
                float ex = exj[j];
                den += ex;
                acc[0] += ex * bf16lo(wv[j].x); acc[1] += ex * bf16hi(wv[j].x);
                acc[2] += ex * bf16lo(wv[j].y); acc[3] += ex * bf16hi(wv[j].y);
                acc[4] += ex * bf16lo(wv[j].z); acc[5] += ex * bf16hi(wv[j].z);
                acc[6] += ex * bf16lo(wv[j].w); acc[7] += ex * bf16hi(wv[j].w);
            }
        }
    }
    if (dl < nd) {
        float inv = (c1 > c0) ? 1.f / den : 0.f;
        float o[8];
        #pragma unroll
        for (int j = 0; j < 8; ++j) {
            float v = acc[j] * inv;
            o[j] = (v > 0.f) ? v : expm1f(v);
        }
        float* op = &out[(dstbase + dl) * OUTF + jg];
        *(float4*)(op + 0) = make_float4(o[0], o[1], o[2], o[3]);
        *(float4*)(op + 4) = make_float4(o[4], o[5], o[6], o[7]);
    }
}

extern "C" void kernel_launch(void* const* d_in, const int* in_sizes, int n_in,
                              void* d_out, int out_size, void* d_ws, size_t ws_size,
                              hipStream_t stream) {
    const float* h  = (const float*)d_in[0];
    const int*   ei = (const int*)d_in[1];    // [2, E]: first E = src, next E = dst
    const float* W  = (const float*)d_in[2];
    const float* a  = (const float*)d_in[3];
    const int* src = ei;
    const int* dst = ei + GE;

    float* ws = (float*)d_ws;
    float* s1 = ws;                                          // N
    float* s2 = s1 + GN;                                     // N
    unsigned short* Whb = (unsigned short*)(s2 + GN);        // N*64 bf16
    int* epacked = (int*)(Whb + (size_t)GN * OUTF);          // NB*CAP (4.8 MB)
    int* ccount  = epacked + (size_t)NB * CAP;               // NB
    float* out = (float*)d_out;

    hipMemsetAsync(ccount, 0, NB * sizeof(int), stream);     // 6.3 KB, capture-safe
    k_front<<<NCH + GT, 256, 0, stream>>>(h, W, a, src, dst, Whb, s1, s2,
                                          ccount, epacked);
    k_fgather<<<NB, 256, 0, stream>>>(ccount, epacked, s1, s2, Whb, out);
}